// Round 1
// baseline (874.535 us; speedup 1.0000x reference)
//
#include <hip/hip_runtime.h>
#include <hip/hip_bf16.h>

#define NN 100000        // nodes
#define NE 3200000       // edges
#define FF 32            // node features
#define LL 50            // node labels
#define ELB 10           // edge labels
#define KK 16            // out dim
#define NB_SCAN 391      // ceil(NN/256)

// ---------- CSR build ----------
__global__ __launch_bounds__(256) void count_kernel(const int* __restrict__ dst,
                                                    int* __restrict__ deg) {
    int i = blockIdx.x * 256 + threadIdx.x;   // grid exactly NE/256
    atomicAdd(&deg[dst[i]], 1);
}

__global__ __launch_bounds__(256) void scan1_kernel(const int* __restrict__ deg,
                                                    int* __restrict__ off,
                                                    int* __restrict__ bsum) {
    __shared__ int tmp[256];
    int tid = threadIdx.x;
    int gid = blockIdx.x * 256 + tid;
    int v = (gid < NN) ? deg[gid] : 0;
    tmp[tid] = v;
    __syncthreads();
    for (int ofs = 1; ofs < 256; ofs <<= 1) {
        int t = (tid >= ofs) ? tmp[tid - ofs] : 0;
        __syncthreads();
        tmp[tid] += t;
        __syncthreads();
    }
    if (gid < NN) off[gid] = tmp[tid] - v;          // exclusive within block
    if (tid == 255) bsum[blockIdx.x] = tmp[255];    // block total
}

__global__ __launch_bounds__(512) void scan2_kernel(const int* __restrict__ bsum,
                                                    int* __restrict__ bscan) {
    __shared__ int tmp[512];
    int tid = threadIdx.x;
    int v = (tid < NB_SCAN) ? bsum[tid] : 0;
    tmp[tid] = v;
    __syncthreads();
    for (int ofs = 1; ofs < 512; ofs <<= 1) {
        int t = (tid >= ofs) ? tmp[tid - ofs] : 0;
        __syncthreads();
        tmp[tid] += t;
        __syncthreads();
    }
    if (tid < NB_SCAN) bscan[tid] = tmp[tid] - v;   // exclusive across blocks
}

__global__ __launch_bounds__(256) void scan3_kernel(int* __restrict__ off,
                                                    const int* __restrict__ bscan,
                                                    int* __restrict__ cursor) {
    int gid = blockIdx.x * 256 + threadIdx.x;
    if (gid < NN) {
        int o = off[gid] + bscan[blockIdx.x];
        off[gid] = o;
        cursor[gid] = o;
    }
    if (gid == 0) off[NN] = NE;
}

// pack (weight-table index << 17) | src  — src < 2^17, widx < 25000 < 2^15
__global__ __launch_bounds__(256) void fill_kernel(const int* __restrict__ esrc,
                                                   const int* __restrict__ edst,
                                                   const int* __restrict__ elab,
                                                   const int* __restrict__ labels,
                                                   int* __restrict__ cursor,
                                                   unsigned* __restrict__ packed) {
    int i = blockIdx.x * 256 + threadIdx.x;   // grid exactly NE/256
    int s = esrc[i];
    int d = edst[i];
    int e = elab[i];
    int widx = (labels[s] * LL + labels[d]) * ELB + e;
    int pos = atomicAdd(&cursor[d], 1);
    packed[pos] = ((unsigned)widx << 17) | (unsigned)s;
}

// ---------- conv layer: half-wave (32 lanes) per dst node, lane = feature ----------
__global__ __launch_bounds__(256) void conv_kernel(const float* __restrict__ xin,
                                                   float* __restrict__ hout,
                                                   const int* __restrict__ off,
                                                   const unsigned* __restrict__ packed,
                                                   const float* __restrict__ Wtab,
                                                   const float* __restrict__ bias,
                                                   const int* __restrict__ labels) {
    int hw   = (blockIdx.x * 256 + threadIdx.x) >> 5;   // node id (grid exact)
    int lane = threadIdx.x & 31;
    int s = off[hw];
    int e = off[hw + 1];
    float acc = 0.f;
    int i = s;
    // full chunks of 32 edges
    for (; i + 32 <= e; i += 32) {
        unsigned p = packed[i + lane];
        float w = Wtab[p >> 17];
        unsigned so = (p & 0x1FFFFu) << 5;   // src*32
#pragma unroll
        for (int j = 0; j < 32; ++j) {
            acc += __shfl(w, j, 32) * xin[__shfl(so, j, 32) + lane];
        }
    }
    // remainder
    int rem = e - i;
    if (rem > 0) {
        unsigned p = 0u;
        float w = 0.f;
        if (lane < rem) {
            p = packed[i + lane];
            w = Wtab[p >> 17];
        }
        unsigned so = (p & 0x1FFFFu) << 5;
        for (int j = 0; j < rem; ++j) {
            acc += __shfl(w, j, 32) * xin[__shfl(so, j, 32) + lane];
        }
    }
    hout[(hw << 5) + lane] = tanhf(acc + bias[labels[hw]]);
}

// ---------- label pooling: sums[L][F] ----------
__global__ __launch_bounds__(256) void lsum_kernel(const float* __restrict__ h,
                                                   const int* __restrict__ labels,
                                                   float* __restrict__ sums) {
    __shared__ float ls[LL * FF];
    int tid = threadIdx.x;
    for (int i = tid; i < LL * FF; i += 256) ls[i] = 0.f;
    __syncthreads();
    int lane = tid & 31;
    int hw = (blockIdx.x * 256 + tid) >> 5;
    int stride = (gridDim.x * 256) >> 5;
    for (int n = hw; n < NN; n += stride) {
        int l = labels[n];
        atomicAdd(&ls[l * FF + lane], h[(n << 5) + lane]);
    }
    __syncthreads();
    for (int i = tid; i < LL * FF; i += 256) atomicAdd(&sums[i], ls[i]);
}

// ---------- final resize: out[k] = tanh(sum_{l,f} sums[l,f]*Wr[l,f,k] + br[k]) ----------
__global__ __launch_bounds__(256) void resize_kernel(const float* __restrict__ sums,
                                                     const float* __restrict__ Wr,
                                                     const float* __restrict__ br,
                                                     float* __restrict__ out) {
    __shared__ float red[256][KK];
    int tid = threadIdx.x;
    float acc[KK];
#pragma unroll
    for (int k = 0; k < KK; ++k) acc[k] = 0.f;
    for (int p = tid; p < LL * FF; p += 256) {
        float sv = sums[p];
#pragma unroll
        for (int k = 0; k < KK; ++k) acc[k] += sv * Wr[p * KK + k];
    }
#pragma unroll
    for (int k = 0; k < KK; ++k) red[tid][k] = acc[k];
    __syncthreads();
    for (int sft = 128; sft > 0; sft >>= 1) {
        if (tid < sft) {
#pragma unroll
            for (int k = 0; k < KK; ++k) red[tid][k] += red[tid + sft][k];
        }
        __syncthreads();
    }
    if (tid < KK) out[tid] = tanhf(red[0][tid] + br[tid]);
}

extern "C" void kernel_launch(void* const* d_in, const int* in_sizes, int n_in,
                              void* d_out, int out_size, void* d_ws, size_t ws_size,
                              hipStream_t stream) {
    const float* x   = (const float*)d_in[0];
    const float* W1  = (const float*)d_in[1];
    const float* b1  = (const float*)d_in[2];
    const float* W2  = (const float*)d_in[3];
    const float* b2  = (const float*)d_in[4];
    const float* W3  = (const float*)d_in[5];
    const float* b3  = (const float*)d_in[6];
    const float* Wr  = (const float*)d_in[7];
    const float* br  = (const float*)d_in[8];
    const int* labels = (const int*)d_in[9];
    const int* esrc   = (const int*)d_in[10];
    const int* edst   = (const int*)d_in[11];
    const int* elab   = (const int*)d_in[12];
    float* out = (float*)d_out;

    char* ws = (char*)d_ws;
    size_t o = 0;
    auto alloc = [&](size_t bytes) -> void* {
        void* p = ws + o;
        o += (bytes + 255) & ~(size_t)255;
        return p;
    };
    int* deg       = (int*)alloc((NN + 1) * sizeof(int));
    int* off       = (int*)alloc((NN + 1) * sizeof(int));
    int* cursor    = (int*)alloc((NN + 1) * sizeof(int));
    int* bsum      = (int*)alloc(512 * sizeof(int));
    int* bscan     = (int*)alloc(512 * sizeof(int));
    unsigned* packed = (unsigned*)alloc((size_t)NE * sizeof(unsigned));
    float* h1      = (float*)alloc((size_t)NN * FF * sizeof(float));
    float* h2      = (float*)alloc((size_t)NN * FF * sizeof(float));
    float* sums    = (float*)alloc(LL * FF * sizeof(float));
    // total ~39.5 MB of d_ws

    hipMemsetAsync(deg, 0, (NN + 1) * sizeof(int), stream);
    hipMemsetAsync(sums, 0, LL * FF * sizeof(float), stream);

    count_kernel<<<NE / 256, 256, 0, stream>>>(edst, deg);
    scan1_kernel<<<NB_SCAN, 256, 0, stream>>>(deg, off, bsum);
    scan2_kernel<<<1, 512, 0, stream>>>(bsum, bscan);
    scan3_kernel<<<NB_SCAN, 256, 0, stream>>>(off, bscan, cursor);
    fill_kernel<<<NE / 256, 256, 0, stream>>>(esrc, edst, elab, labels, cursor, packed);

    conv_kernel<<<NN * FF / 256, 256, 0, stream>>>(x,  h1, off, packed, W1, b1, labels);
    conv_kernel<<<NN * FF / 256, 256, 0, stream>>>(h1, h2, off, packed, W2, b2, labels);
    conv_kernel<<<NN * FF / 256, 256, 0, stream>>>(h2, h1, off, packed, W3, b3, labels);

    lsum_kernel<<<128, 256, 0, stream>>>(h1, labels, sums);
    resize_kernel<<<1, 256, 0, stream>>>(sums, Wr, br, out);
}

// Round 2
// 431.459 us; speedup vs baseline: 2.0269x; 2.0269x over previous
//
#include <hip/hip_runtime.h>
#include <hip/hip_bf16.h>

#define NN 100000        // nodes
#define NE 3200000       // edges
#define FF 32            // node features
#define LL 50            // node labels
#define ELB 10           // edge labels
#define KK 16            // out dim

#define CH 8192          // edges per p1 block
#define NBLK_P1 391      // ceil(NE/CH)
#define NBUK 782         // ceil(NN/128) node buckets of 128 nodes
#define CAP 4608         // slots per bucket (mean 4096, +8 sigma)

// ---------- cursor init: cursor[b] = b*CAP ----------
__global__ __launch_bounds__(256) void cursor_init(int* __restrict__ cursor) {
    int i = blockIdx.x * 256 + threadIdx.x;
    if (i < NBUK) cursor[i] = i * CAP;
}

// ---------- phase 1: bucket scatter with per-(block,bucket) contiguous runs ----------
// rec u64 = packed(32b: widx<<17|src) << 7 | dst_local(7b)
__global__ __launch_bounds__(256) void p1_scatter(const int* __restrict__ esrc,
                                                  const int* __restrict__ edst,
                                                  const int* __restrict__ elab,
                                                  const int* __restrict__ labels,
                                                  int* __restrict__ cursor,
                                                  unsigned long long* __restrict__ recs) {
    __shared__ int lcnt[NBUK];
    __shared__ int lbase[NBUK];
    int tid = threadIdx.x;
    for (int i = tid; i < NBUK; i += 256) lcnt[i] = 0;
    __syncthreads();
    long e0 = (long)blockIdx.x * CH;
    // pass A: count per bucket
    for (int i = tid; i < CH; i += 256) {
        long e = e0 + i;
        if (e < NE) atomicAdd(&lcnt[edst[e] >> 7], 1);
    }
    __syncthreads();
    // pass B: reserve runs
    for (int i = tid; i < NBUK; i += 256) {
        int c = lcnt[i];
        lbase[i] = c ? atomicAdd(&cursor[i], c) : 0;
        lcnt[i] = 0;   // reuse as local cursor
    }
    __syncthreads();
    // pass C: place (chunk is L2-hot from pass A)
    for (int i = tid; i < CH; i += 256) {
        long e = e0 + i;
        if (e < NE) {
            int s = esrc[e], d = edst[e], el = elab[e];
            int widx = (labels[s] * LL + labels[d]) * ELB + el;
            unsigned p = ((unsigned)widx << 17) | (unsigned)s;
            int b = d >> 7;
            int ofs = atomicAdd(&lcnt[b], 1);
            long pos = (long)lbase[b] + ofs;
            if (pos < (long)(b + 1) * CAP)   // overflow guard (8-sigma, never in practice)
                recs[pos] = ((unsigned long long)p << 7) | (unsigned)(d & 127);
        }
    }
}

// ---------- phase 2: per-bucket exact CSR built in LDS, coalesced flush ----------
__global__ __launch_bounds__(256) void p2_local(const int* __restrict__ cursor,
                                                const unsigned long long* __restrict__ recs,
                                                unsigned* __restrict__ packed,
                                                int* __restrict__ gstart,
                                                int* __restrict__ gcnt) {
    __shared__ int deg[128], loff[128], lcur[128], sc[128];
    __shared__ unsigned outbuf[CAP];
    int b = blockIdx.x, tid = threadIdx.x;
    int base = b * CAP;
    int n = cursor[b] - base;
    if (n > CAP) n = CAP;
    for (int i = tid; i < 128; i += 256) { deg[i] = 0; lcur[i] = 0; }
    __syncthreads();
    for (int i = tid; i < n; i += 256)
        atomicAdd(&deg[(int)(recs[base + i] & 127)], 1);
    __syncthreads();
    // inclusive scan of deg -> sc (Hillis-Steele over 128)
    if (tid < 128) sc[tid] = deg[tid];
    __syncthreads();
    for (int ofs = 1; ofs < 128; ofs <<= 1) {
        int t = 0;
        if (tid < 128 && tid >= ofs) t = sc[tid - ofs];
        __syncthreads();
        if (tid < 128) sc[tid] += t;
        __syncthreads();
    }
    if (tid < 128) {
        int st = sc[tid] - deg[tid];   // exclusive
        loff[tid] = st;
        int node = b * 128 + tid;
        if (node < NN) { gstart[node] = base + st; gcnt[node] = deg[tid]; }
    }
    __syncthreads();
    // place into LDS by local offset
    for (int i = tid; i < n; i += 256) {
        unsigned long long r = recs[base + i];
        int dl = (int)(r & 127);
        int ofs = atomicAdd(&lcur[dl], 1);
        outbuf[loff[dl] + ofs] = (unsigned)(r >> 7);
    }
    __syncthreads();
    // coalesced flush
    for (int i = tid; i < n; i += 256) packed[base + i] = outbuf[i];
}

// ---------- conv layer: half-wave (32 lanes) per dst node, LDS-staged broadcast ----------
__global__ __launch_bounds__(256) void conv_kernel(const float* __restrict__ xin,
                                                   float* __restrict__ hout,
                                                   const int* __restrict__ gstart,
                                                   const int* __restrict__ gcnt,
                                                   const unsigned* __restrict__ packed,
                                                   const float* __restrict__ Wtab,
                                                   const float* __restrict__ bias,
                                                   const int* __restrict__ labels) {
    __shared__ unsigned stage[8][64];   // per half-wave: 32 x (w_bits, src*32)
    int tid = threadIdx.x;
    int hw = tid >> 5, lane = tid & 31;
    int node = (blockIdx.x * 256 + tid) >> 5;   // grid exact: 12500*256/32 = 100000
    int s = gstart[node];
    int n = gcnt[node];
    float acc = 0.f;
    for (int base = 0; base < n; base += 32) {
        float w = 0.f;
        unsigned so = 0u;
        int idx = base + lane;
        if (idx < n) {
            unsigned p = packed[s + idx];
            w = Wtab[p >> 17];
            so = (p & 0x1FFFFu) << 5;   // src*32 (element offset)
        }
        ((uint2*)&stage[hw][0])[lane] = make_uint2(__float_as_uint(w), so);
        __builtin_amdgcn_wave_barrier();   // same-wave DS RAW: DS pipe is in-order
#pragma unroll
        for (int jj = 0; jj < 16; ++jj) {
            uint4 q = ((const uint4*)&stage[hw][0])[jj];   // broadcast read, 2 edges
            acc += __uint_as_float(q.x) * xin[q.y + lane];
            acc += __uint_as_float(q.z) * xin[q.w + lane];
        }
        __builtin_amdgcn_wave_barrier();
    }
    hout[(node << 5) + lane] = tanhf(acc + bias[labels[node]]);
}

// ---------- label pooling: sums[L][F] ----------
__global__ __launch_bounds__(256) void lsum_kernel(const float* __restrict__ h,
                                                   const int* __restrict__ labels,
                                                   float* __restrict__ sums) {
    __shared__ float ls[LL * FF];
    int tid = threadIdx.x;
    for (int i = tid; i < LL * FF; i += 256) ls[i] = 0.f;
    __syncthreads();
    int lane = tid & 31;
    int hw = (blockIdx.x * 256 + tid) >> 5;
    int stride = (gridDim.x * 256) >> 5;
    for (int nd = hw; nd < NN; nd += stride) {
        int l = labels[nd];
        atomicAdd(&ls[l * FF + lane], h[(nd << 5) + lane]);
    }
    __syncthreads();
    for (int i = tid; i < LL * FF; i += 256) atomicAdd(&sums[i], ls[i]);
}

// ---------- final resize ----------
__global__ __launch_bounds__(256) void resize_kernel(const float* __restrict__ sums,
                                                     const float* __restrict__ Wr,
                                                     const float* __restrict__ br,
                                                     float* __restrict__ out) {
    __shared__ float red[256][KK];
    int tid = threadIdx.x;
    float acc[KK];
#pragma unroll
    for (int k = 0; k < KK; ++k) acc[k] = 0.f;
    for (int p = tid; p < LL * FF; p += 256) {
        float sv = sums[p];
#pragma unroll
        for (int k = 0; k < KK; ++k) acc[k] += sv * Wr[p * KK + k];
    }
#pragma unroll
    for (int k = 0; k < KK; ++k) red[tid][k] = acc[k];
    __syncthreads();
    for (int sft = 128; sft > 0; sft >>= 1) {
        if (tid < sft) {
#pragma unroll
            for (int k = 0; k < KK; ++k) red[tid][k] += red[tid + sft][k];
        }
        __syncthreads();
    }
    if (tid < KK) out[tid] = tanhf(red[0][tid] + br[tid]);
}

extern "C" void kernel_launch(void* const* d_in, const int* in_sizes, int n_in,
                              void* d_out, int out_size, void* d_ws, size_t ws_size,
                              hipStream_t stream) {
    const float* x   = (const float*)d_in[0];
    const float* W1  = (const float*)d_in[1];
    const float* b1  = (const float*)d_in[2];
    const float* W2  = (const float*)d_in[3];
    const float* b2  = (const float*)d_in[4];
    const float* W3  = (const float*)d_in[5];
    const float* b3  = (const float*)d_in[6];
    const float* Wr  = (const float*)d_in[7];
    const float* br  = (const float*)d_in[8];
    const int* labels = (const int*)d_in[9];
    const int* esrc   = (const int*)d_in[10];
    const int* edst   = (const int*)d_in[11];
    const int* elab   = (const int*)d_in[12];
    float* out = (float*)d_out;

    char* ws = (char*)d_ws;
    size_t o = 0;
    auto alloc = [&](size_t bytes) -> void* {
        void* p = ws + o;
        o += (bytes + 255) & ~(size_t)255;
        return p;
    };
    // region A: recs (28.8 MB) overlaps h1+h2 (25.6 MB) — recs dead after p2,
    // h1 first written by conv1 which is stream-ordered after p2.
    char* regionA = (char*)alloc((size_t)NBUK * CAP * sizeof(unsigned long long));
    unsigned long long* recs = (unsigned long long*)regionA;
    float* h1 = (float*)regionA;
    float* h2 = (float*)(regionA + (size_t)NN * FF * sizeof(float));

    unsigned* packed = (unsigned*)alloc((size_t)NBUK * CAP * sizeof(unsigned));
    int* cursor = (int*)alloc(NBUK * sizeof(int));
    int* gstart = (int*)alloc(NN * sizeof(int));
    int* gcnt   = (int*)alloc(NN * sizeof(int));
    float* sums = (float*)alloc(LL * FF * sizeof(float));
    // total ~44.5 MB of d_ws

    hipMemsetAsync(sums, 0, LL * FF * sizeof(float), stream);
    cursor_init<<<(NBUK + 255) / 256, 256, 0, stream>>>(cursor);
    p1_scatter<<<NBLK_P1, 256, 0, stream>>>(esrc, edst, elab, labels, cursor, recs);
    p2_local<<<NBUK, 256, 0, stream>>>(cursor, recs, packed, gstart, gcnt);

    conv_kernel<<<NN * FF / 256, 256, 0, stream>>>(x,  h1, gstart, gcnt, packed, W1, b1, labels);
    conv_kernel<<<NN * FF / 256, 256, 0, stream>>>(h1, h2, gstart, gcnt, packed, W2, b2, labels);
    conv_kernel<<<NN * FF / 256, 256, 0, stream>>>(h2, h1, gstart, gcnt, packed, W3, b3, labels);

    lsum_kernel<<<128, 256, 0, stream>>>(h1, labels, sums);
    resize_kernel<<<1, 256, 0, stream>>>(sums, Wr, br, out);
}

// Round 3
// 366.234 us; speedup vs baseline: 2.3879x; 1.1781x over previous
//
#include <hip/hip_runtime.h>
#include <hip/hip_bf16.h>

#define NN 100000        // nodes
#define NE 3200000       // edges
#define FF 32            // node features
#define LL 50            // node labels
#define ELB 10           // edge labels
#define KK 16            // out dim

#define CH 16384         // edges per p1 block
#define NBLK_P1 196      // ceil(NE/CH)
#define NBUK 391         // ceil(NN/256) buckets of 256 nodes
#define CAP 9216         // slots per bucket (mean 8192, +11 sigma)

// ---------- cursor init: cursor[b] = b*CAP ----------
__global__ __launch_bounds__(256) void cursor_init(int* __restrict__ cursor) {
    int i = blockIdx.x * 256 + threadIdx.x;
    if (i < NBUK) cursor[i] = i * CAP;
}

// ---------- phase 1: bucket scatter, per-(block,bucket) contiguous runs ----------
// rec u64 = packed(32b: widx<<17|src) << 8 | dst_local(8b)
__global__ __launch_bounds__(512) void p1_scatter(const int* __restrict__ esrc,
                                                  const int* __restrict__ edst,
                                                  const int* __restrict__ elab,
                                                  const int* __restrict__ labels,
                                                  int* __restrict__ cursor,
                                                  unsigned long long* __restrict__ recs) {
    __shared__ int lcnt[NBUK];
    __shared__ int lbase[NBUK];
    int tid = threadIdx.x;
    for (int i = tid; i < NBUK; i += 512) lcnt[i] = 0;
    __syncthreads();
    long e0 = (long)blockIdx.x * CH;
    int cnt = (int)((NE - e0 < CH) ? (NE - e0) : CH);   // divisible by 4
    int nq = cnt >> 2;
    const int4* edst4 = (const int4*)(edst + e0);
    const int4* esrc4 = (const int4*)(esrc + e0);
    const int4* elab4 = (const int4*)(elab + e0);
    // pass A: count per bucket (vectorized)
    for (int i = tid; i < nq; i += 512) {
        int4 d = edst4[i];
        atomicAdd(&lcnt[d.x >> 8], 1);
        atomicAdd(&lcnt[d.y >> 8], 1);
        atomicAdd(&lcnt[d.z >> 8], 1);
        atomicAdd(&lcnt[d.w >> 8], 1);
    }
    __syncthreads();
    // pass B: reserve contiguous runs (cursor holds absolute positions)
    for (int i = tid; i < NBUK; i += 512) {
        int c = lcnt[i];
        lbase[i] = c ? atomicAdd(&cursor[i], c) : 0;
        lcnt[i] = 0;   // reuse as local cursor
    }
    __syncthreads();
    // pass C: place (chunk L2-hot from pass A)
    for (int i = tid; i < nq; i += 512) {
        int4 s4 = esrc4[i];
        int4 d4 = edst4[i];
        int4 l4 = elab4[i];
#pragma unroll
        for (int k = 0; k < 4; ++k) {
            int s  = (&s4.x)[k];
            int d  = (&d4.x)[k];
            int el = (&l4.x)[k];
            int widx = labels[s] * (LL * ELB) + labels[d] * ELB + el;
            unsigned p = ((unsigned)widx << 17) | (unsigned)s;
            int b = d >> 8;
            int ofs = atomicAdd(&lcnt[b], 1);
            int pos = lbase[b] + ofs;
            if (pos < (b + 1) * CAP)   // 11-sigma overflow guard
                recs[pos] = ((unsigned long long)p << 8) | (unsigned)(d & 255);
        }
    }
}

// ---------- phase 2: per-bucket exact CSR; direct scatter into L2-hot region ----------
__global__ __launch_bounds__(256) void p2_local(const int* __restrict__ cursor,
                                                const unsigned long long* __restrict__ recs,
                                                unsigned* __restrict__ packed,
                                                int* __restrict__ gstart,
                                                int* __restrict__ gcnt) {
    __shared__ int deg[256], loff[256], lcur[256], sc[256];
    int b = blockIdx.x, tid = threadIdx.x;
    int base = b * CAP;
    int n = cursor[b] - base;
    if (n > CAP) n = CAP;
    deg[tid] = 0;
    lcur[tid] = 0;
    __syncthreads();
    for (int i = tid; i < n; i += 256)
        atomicAdd(&deg[(int)(recs[base + i] & 255)], 1);
    __syncthreads();
    sc[tid] = deg[tid];
    __syncthreads();
    for (int ofs = 1; ofs < 256; ofs <<= 1) {
        int t = (tid >= ofs) ? sc[tid - ofs] : 0;
        __syncthreads();
        sc[tid] += t;
        __syncthreads();
    }
    {
        int st = sc[tid] - deg[tid];   // exclusive
        loff[tid] = st;
        int node = (b << 8) + tid;
        if (node < NN) { gstart[node] = base + st; gcnt[node] = deg[tid]; }
    }
    __syncthreads();
    // direct scatter: block's 36 KB packed region is L2-resident & fully written
    for (int i = tid; i < n; i += 256) {
        unsigned long long r = recs[base + i];
        int dl = (int)(r & 255);
        int ofs = atomicAdd(&lcur[dl], 1);
        packed[base + loff[dl] + ofs] = (unsigned)(r >> 8);
    }
}

// ---------- x fp32 -> bf16 ----------
__global__ __launch_bounds__(256) void xcvt_kernel(const float* __restrict__ x,
                                                   unsigned short* __restrict__ xb) {
    int i = blockIdx.x * 256 + threadIdx.x;   // grid exact: NN*FF/2/256 = 6250
    float2 v = ((const float2*)x)[i];
    __hip_bfloat162 h2 = __float22bfloat162_rn(v);
    ((__hip_bfloat162*)xb)[i] = h2;
}

// ---------- conv layer: half-wave per dst node, LDS-staged broadcast, bf16 gather ----------
__global__ __launch_bounds__(256) void conv_kernel(const unsigned short* __restrict__ xin,
                                                   unsigned short* __restrict__ hout,
                                                   const int* __restrict__ gstart,
                                                   const int* __restrict__ gcnt,
                                                   const unsigned* __restrict__ packed,
                                                   const float* __restrict__ Wtab,
                                                   const float* __restrict__ bias,
                                                   const int* __restrict__ labels) {
    __shared__ unsigned stage[8][64];   // per half-wave: 32 x (w_bits, src*32)
    int tid = threadIdx.x;
    int hw = tid >> 5, lane = tid & 31;
    int node = (blockIdx.x * 256 + tid) >> 5;   // grid exact: 12500*256/32 = 100000
    int s = gstart[node];
    int n = gcnt[node];
    float acc = 0.f;
    for (int base = 0; base < n; base += 32) {
        float w = 0.f;
        unsigned so = 0u;
        int idx = base + lane;
        if (idx < n) {
            unsigned p = packed[s + idx];
            w = Wtab[p >> 17];
            so = (p & 0x1FFFFu) << 5;   // src*32 (element offset)
        }
        ((uint2*)&stage[hw][0])[lane] = make_uint2(__float_as_uint(w), so);
        __builtin_amdgcn_wave_barrier();   // same-wave DS RAW: DS pipe is in-order
#pragma unroll
        for (int jj = 0; jj < 16; ++jj) {
            uint4 q = ((const uint4*)&stage[hw][0])[jj];   // broadcast read, 2 edges
            acc += __uint_as_float(q.x) *
                   __uint_as_float((unsigned)xin[q.y + lane] << 16);
            acc += __uint_as_float(q.z) *
                   __uint_as_float((unsigned)xin[q.w + lane] << 16);
        }
        __builtin_amdgcn_wave_barrier();
    }
    float v = tanhf(acc + bias[labels[node]]);
    __hip_bfloat16 hb = __float2bfloat16(v);
    hout[(node << 5) + lane] = *(unsigned short*)&hb;
}

// ---------- label pooling: sums[L][F] ----------
__global__ __launch_bounds__(256) void lsum_kernel(const unsigned short* __restrict__ h,
                                                   const int* __restrict__ labels,
                                                   float* __restrict__ sums) {
    __shared__ float ls[LL * FF];
    int tid = threadIdx.x;
    for (int i = tid; i < LL * FF; i += 256) ls[i] = 0.f;
    __syncthreads();
    int lane = tid & 31;
    int hwv = (blockIdx.x * 256 + tid) >> 5;
    int stride = (gridDim.x * 256) >> 5;
    for (int nd = hwv; nd < NN; nd += stride) {
        int l = labels[nd];
        float hv = __uint_as_float((unsigned)h[(nd << 5) + lane] << 16);
        atomicAdd(&ls[l * FF + lane], hv);
    }
    __syncthreads();
    for (int i = tid; i < LL * FF; i += 256) atomicAdd(&sums[i], ls[i]);
}

// ---------- final resize ----------
__global__ __launch_bounds__(256) void resize_kernel(const float* __restrict__ sums,
                                                     const float* __restrict__ Wr,
                                                     const float* __restrict__ br,
                                                     float* __restrict__ out) {
    __shared__ float red[256][KK];
    int tid = threadIdx.x;
    float acc[KK];
#pragma unroll
    for (int k = 0; k < KK; ++k) acc[k] = 0.f;
    for (int p = tid; p < LL * FF; p += 256) {
        float sv = sums[p];
#pragma unroll
        for (int k = 0; k < KK; ++k) acc[k] += sv * Wr[p * KK + k];
    }
#pragma unroll
    for (int k = 0; k < KK; ++k) red[tid][k] = acc[k];
    __syncthreads();
    for (int sft = 128; sft > 0; sft >>= 1) {
        if (tid < sft) {
#pragma unroll
            for (int k = 0; k < KK; ++k) red[tid][k] += red[tid + sft][k];
        }
        __syncthreads();
    }
    if (tid < KK) out[tid] = tanhf(red[0][tid] + br[tid]);
}

extern "C" void kernel_launch(void* const* d_in, const int* in_sizes, int n_in,
                              void* d_out, int out_size, void* d_ws, size_t ws_size,
                              hipStream_t stream) {
    const float* x   = (const float*)d_in[0];
    const float* W1  = (const float*)d_in[1];
    const float* b1  = (const float*)d_in[2];
    const float* W2  = (const float*)d_in[3];
    const float* b2  = (const float*)d_in[4];
    const float* W3  = (const float*)d_in[5];
    const float* b3  = (const float*)d_in[6];
    const float* Wr  = (const float*)d_in[7];
    const float* br  = (const float*)d_in[8];
    const int* labels = (const int*)d_in[9];
    const int* esrc   = (const int*)d_in[10];
    const int* edst   = (const int*)d_in[11];
    const int* elab   = (const int*)d_in[12];
    float* out = (float*)d_out;

    char* ws = (char*)d_ws;
    size_t o = 0;
    auto alloc = [&](size_t bytes) -> void* {
        void* p = ws + o;
        o += (bytes + 255) & ~(size_t)255;
        return p;
    };
    // region A: recs (28.8 MB) later reused for h1 / h2 / xb (bf16, 6.4 MB each).
    // recs is dead after p2; xcvt runs AFTER p2 so xb doesn't get clobbered.
    char* regionA = (char*)alloc((size_t)NBUK * CAP * sizeof(unsigned long long));
    unsigned long long* recs = (unsigned long long*)regionA;
    unsigned short* h1 = (unsigned short*)regionA;
    unsigned short* h2 = (unsigned short*)(regionA + (size_t)NN * FF * sizeof(unsigned short));
    unsigned short* xb = (unsigned short*)(regionA + 2 * (size_t)NN * FF * sizeof(unsigned short));

    unsigned* packed = (unsigned*)alloc((size_t)NBUK * CAP * sizeof(unsigned));
    int* cursor = (int*)alloc(NBUK * sizeof(int));
    int* gstart = (int*)alloc(NN * sizeof(int));
    int* gcnt   = (int*)alloc(NN * sizeof(int));
    float* sums = (float*)alloc(LL * FF * sizeof(float));
    // total ~44.2 MB of d_ws

    hipMemsetAsync(sums, 0, LL * FF * sizeof(float), stream);
    cursor_init<<<(NBUK + 255) / 256, 256, 0, stream>>>(cursor);
    p1_scatter<<<NBLK_P1, 512, 0, stream>>>(esrc, edst, elab, labels, cursor, recs);
    p2_local<<<NBUK, 256, 0, stream>>>(cursor, recs, packed, gstart, gcnt);
    xcvt_kernel<<<NN * FF / 512, 256, 0, stream>>>(x, xb);

    conv_kernel<<<NN * FF / 256, 256, 0, stream>>>(xb, h1, gstart, gcnt, packed, W1, b1, labels);
    conv_kernel<<<NN * FF / 256, 256, 0, stream>>>(h1, h2, gstart, gcnt, packed, W2, b2, labels);
    conv_kernel<<<NN * FF / 256, 256, 0, stream>>>(h2, h1, gstart, gcnt, packed, W3, b3, labels);

    lsum_kernel<<<128, 256, 0, stream>>>(h1, labels, sums);
    resize_kernel<<<1, 256, 0, stream>>>(sums, Wr, br, out);
}

// Round 4
// 318.143 us; speedup vs baseline: 2.7489x; 1.1512x over previous
//
#include <hip/hip_runtime.h>
#include <hip/hip_bf16.h>
#include <hip/hip_fp8.h>

#define NN 100000        // nodes
#define NE 3200000       // edges
#define FF 32            // node features
#define LL 50            // node labels
#define ELB 10           // edge labels
#define KK 16            // out dim

#define CH 8192          // edges per p1 block
#define NBLK_P1 391      // ceil(NE/CH)
#define NBUK 391         // ceil(NN/256) buckets of 256 nodes
#define CAP 9216         // slots per bucket (mean 8192, sigma ~90 -> +11 sigma)

typedef float floatx2 __attribute__((ext_vector_type(2)));

__device__ __forceinline__ float fast_tanh(float x) {
    float e = __expf(2.0f * x);
    return 1.0f - 2.0f / (e + 1.0f);   // saturates correctly at +/-1
}

// ---------- phase 1: x->fp8 convert + bucket scatter of u32 recs ----------
// rec u32 = src(17b)<<12 | elab(4b)<<8 | dst_local(8b)
__global__ __launch_bounds__(512) void p1_scatter(const int* __restrict__ esrc,
                                                  const int* __restrict__ edst,
                                                  const int* __restrict__ elab,
                                                  const float* __restrict__ x,
                                                  unsigned* __restrict__ xb,
                                                  int* __restrict__ cursor,
                                                  unsigned* __restrict__ recs) {
    __shared__ int lcnt[NBUK];
    __shared__ int lbase[NBUK];
    __shared__ int sdst[CH];          // 32 KB: chunk's dst cached for pass C
    int tid = threadIdx.x;
    // x -> fp8 (independent work, folded in to save a launch)
    for (int i = blockIdx.x * 512 + tid; i < NN * FF / 4; i += NBLK_P1 * 512) {
        float4 v = ((const float4*)x)[i];
        __hip_fp8_e4m3 a(v.x), b(v.y), c(v.z), d(v.w);
        xb[i] = (unsigned)a.__x | ((unsigned)b.__x << 8) |
                ((unsigned)c.__x << 16) | ((unsigned)d.__x << 24);
    }
    for (int i = tid; i < NBUK; i += 512) lcnt[i] = 0;
    __syncthreads();
    long e0 = (long)blockIdx.x * CH;
    long rem = NE - e0;
    int cnt = rem < CH ? (int)rem : CH;   // always divisible by 4
    int nq = cnt >> 2;
    const int4* edst4 = (const int4*)(edst + e0);
    const int4* esrc4 = (const int4*)(esrc + e0);
    const int4* elab4 = (const int4*)(elab + e0);
    // pass A: count per bucket, stash dst in LDS
    for (int i = tid; i < nq; i += 512) {
        int4 d = edst4[i];
        ((int4*)sdst)[i] = d;
        atomicAdd(&lcnt[d.x >> 8], 1);
        atomicAdd(&lcnt[d.y >> 8], 1);
        atomicAdd(&lcnt[d.z >> 8], 1);
        atomicAdd(&lcnt[d.w >> 8], 1);
    }
    __syncthreads();
    // pass B: reserve contiguous runs (cursor is relative, zero-init by memset)
    for (int i = tid; i < NBUK; i += 512) {
        int c = lcnt[i];
        lbase[i] = c ? atomicAdd(&cursor[i], c) : 0;
        lcnt[i] = 0;   // reuse as local cursor
    }
    __syncthreads();
    // pass C: place
    for (int i = tid; i < nq; i += 512) {
        int4 s4 = esrc4[i];
        int4 l4 = elab4[i];
        int4 d4 = ((const int4*)sdst)[i];
#pragma unroll
        for (int k = 0; k < 4; ++k) {
            int s  = (&s4.x)[k];
            int d  = (&d4.x)[k];
            int el = (&l4.x)[k];
            int b = d >> 8;
            int ofs = atomicAdd(&lcnt[b], 1);
            int rel = lbase[b] + ofs;
            if (rel < CAP)   // 11-sigma overflow guard
                recs[b * CAP + rel] =
                    ((unsigned)s << 12) | ((unsigned)el << 8) | (unsigned)(d & 255);
        }
    }
}

// ---------- phase 2: per-bucket exact CSR + widx resolve ----------
__global__ __launch_bounds__(256) void p2_local(const int* __restrict__ cursor,
                                                const unsigned* __restrict__ recs,
                                                const int* __restrict__ labels,
                                                unsigned* __restrict__ packed,
                                                int* __restrict__ gstart,
                                                int* __restrict__ gcnt) {
    __shared__ int deg[256], loff[256], lcur[256], sc[256], labd[256];
    int b = blockIdx.x, tid = threadIdx.x;
    int base = b * CAP;
    int n = cursor[b];
    if (n > CAP) n = CAP;
    int node = (b << 8) + tid;
    deg[tid] = 0;
    lcur[tid] = 0;
    labd[tid] = (node < NN) ? labels[node] : 0;
    __syncthreads();
    for (int i = tid; i < n; i += 256)
        atomicAdd(&deg[(int)(recs[base + i] & 255)], 1);
    __syncthreads();
    sc[tid] = deg[tid];
    __syncthreads();
    for (int ofs = 1; ofs < 256; ofs <<= 1) {
        int t = (tid >= ofs) ? sc[tid - ofs] : 0;
        __syncthreads();
        sc[tid] += t;
        __syncthreads();
    }
    loff[tid] = sc[tid] - deg[tid];   // exclusive
    if (node < NN) { gstart[node] = base + loff[tid]; gcnt[node] = deg[tid]; }
    __syncthreads();
    // place + resolve widx (labels[src] is a divergent L2 gather, 400 KB table)
    for (int i = tid; i < n; i += 256) {
        unsigned r = recs[base + i];
        int dl  = (int)(r & 255);
        int el  = (int)((r >> 8) & 15);
        int src = (int)(r >> 12);
        int widx = labels[src] * (LL * ELB) + labd[dl] * ELB + el;
        int ofs = atomicAdd(&lcur[dl], 1);
        packed[base + loff[dl] + ofs] = ((unsigned)widx << 17) | (unsigned)src;
    }
}

// ---------- conv: half-wave per node, 8 lanes/row fp8 gather, 4 edges/instr ----------
__global__ __launch_bounds__(256) void conv_kernel(const unsigned char* __restrict__ xin,
                                                   unsigned char* __restrict__ hout,
                                                   const int* __restrict__ gstart,
                                                   const int* __restrict__ gcnt,
                                                   const unsigned* __restrict__ packed,
                                                   const float* __restrict__ Wtab,
                                                   const float* __restrict__ bias,
                                                   const int* __restrict__ labels) {
    __shared__ unsigned stage[8][64];   // per half-wave: 32 x (w_bits, src*32 byte-off)
    int tid = threadIdx.x;
    int hw = tid >> 5, lane = tid & 31;
    int node = (blockIdx.x << 3) + hw;   // grid exact: 12500*8 = 100000
    int s = gstart[node];
    int n = gcnt[node];
    int eg = lane >> 3;          // edge subgroup 0..3
    int fg = (lane & 7) << 2;    // feature byte offset 0..28
    float4 acc = {0.f, 0.f, 0.f, 0.f};
    for (int base = 0; base < n; base += 32) {
        float w = 0.f;
        unsigned so = 0u;
        int idx = base + lane;
        if (idx < n) {
            unsigned p = packed[s + idx];
            w = Wtab[p >> 17];
            so = (p & 0x1FFFFu) << 5;   // src * 32 bytes (fp8 row)
        }
        ((uint2*)&stage[hw][0])[lane] = make_uint2(__float_as_uint(w), so);
        __builtin_amdgcn_wave_barrier();   // same-wave DS RAW: DS pipe in-order
#pragma unroll
        for (int j = 0; j < 8; ++j) {
            uint2 ws = ((const uint2*)&stage[hw][0])[j * 4 + eg];
            unsigned pv = *(const unsigned*)(xin + ws.y + fg);   // 4 fp8 feats
            floatx2 lo = __builtin_amdgcn_cvt_pk_f32_fp8((int)pv, false);
            floatx2 hi = __builtin_amdgcn_cvt_pk_f32_fp8((int)pv, true);
            float we = __uint_as_float(ws.x);
            acc.x += we * lo.x;
            acc.y += we * lo.y;
            acc.z += we * hi.x;
            acc.w += we * hi.y;
        }
        __builtin_amdgcn_wave_barrier();
    }
    // reduce across the 4 edge subgroups (lanes differing in bits 3,4)
    acc.x += __shfl_xor(acc.x, 8);  acc.y += __shfl_xor(acc.y, 8);
    acc.z += __shfl_xor(acc.z, 8);  acc.w += __shfl_xor(acc.w, 8);
    acc.x += __shfl_xor(acc.x, 16); acc.y += __shfl_xor(acc.y, 16);
    acc.z += __shfl_xor(acc.z, 16); acc.w += __shfl_xor(acc.w, 16);
    if (lane < 8) {
        float bb = bias[labels[node]];
        __hip_fp8_e4m3 q0(fast_tanh(acc.x + bb));
        __hip_fp8_e4m3 q1(fast_tanh(acc.y + bb));
        __hip_fp8_e4m3 q2(fast_tanh(acc.z + bb));
        __hip_fp8_e4m3 q3(fast_tanh(acc.w + bb));
        unsigned pk = (unsigned)q0.__x | ((unsigned)q1.__x << 8) |
                      ((unsigned)q2.__x << 16) | ((unsigned)q3.__x << 24);
        ((unsigned*)(hout + ((long)node << 5)))[lane] = pk;   // lane==fg/4
    }
}

// ---------- label pooling: sums[L][F] from fp8 h ----------
__global__ __launch_bounds__(256) void lsum_kernel(const unsigned* __restrict__ h,
                                                   const int* __restrict__ labels,
                                                   float* __restrict__ sums) {
    __shared__ float ls[LL * FF];
    int tid = threadIdx.x;
    for (int i = tid; i < LL * FF; i += 256) ls[i] = 0.f;
    __syncthreads();
    for (int i = blockIdx.x * 256 + tid; i < NN * 8; i += gridDim.x * 256) {
        unsigned pv = h[i];
        int nodei = i >> 3;
        int fb = (i & 7) << 2;
        int l = labels[nodei];
        floatx2 lo = __builtin_amdgcn_cvt_pk_f32_fp8((int)pv, false);
        floatx2 hi = __builtin_amdgcn_cvt_pk_f32_fp8((int)pv, true);
        float* bp = &ls[l * FF + fb];
        atomicAdd(bp + 0, lo.x);
        atomicAdd(bp + 1, lo.y);
        atomicAdd(bp + 2, hi.x);
        atomicAdd(bp + 3, hi.y);
    }
    __syncthreads();
    for (int i = tid; i < LL * FF; i += 256) atomicAdd(&sums[i], ls[i]);
}

// ---------- final resize ----------
__global__ __launch_bounds__(256) void resize_kernel(const float* __restrict__ sums,
                                                     const float* __restrict__ Wr,
                                                     const float* __restrict__ br,
                                                     float* __restrict__ out) {
    __shared__ float red[256][KK];
    int tid = threadIdx.x;
    float acc[KK];
#pragma unroll
    for (int k = 0; k < KK; ++k) acc[k] = 0.f;
    for (int p = tid; p < LL * FF; p += 256) {
        float sv = sums[p];
#pragma unroll
        for (int k = 0; k < KK; ++k) acc[k] += sv * Wr[p * KK + k];
    }
#pragma unroll
    for (int k = 0; k < KK; ++k) red[tid][k] = acc[k];
    __syncthreads();
    for (int sft = 128; sft > 0; sft >>= 1) {
        if (tid < sft) {
#pragma unroll
            for (int k = 0; k < KK; ++k) red[tid][k] += red[tid + sft][k];
        }
        __syncthreads();
    }
    if (tid < KK) out[tid] = fast_tanh(red[0][tid] + br[tid]);
}

extern "C" void kernel_launch(void* const* d_in, const int* in_sizes, int n_in,
                              void* d_out, int out_size, void* d_ws, size_t ws_size,
                              hipStream_t stream) {
    const float* x   = (const float*)d_in[0];
    const float* W1  = (const float*)d_in[1];
    const float* b1  = (const float*)d_in[2];
    const float* W2  = (const float*)d_in[3];
    const float* b2  = (const float*)d_in[4];
    const float* W3  = (const float*)d_in[5];
    const float* b3  = (const float*)d_in[6];
    const float* Wr  = (const float*)d_in[7];
    const float* br  = (const float*)d_in[8];
    const int* labels = (const int*)d_in[9];
    const int* esrc   = (const int*)d_in[10];
    const int* edst   = (const int*)d_in[11];
    const int* elab   = (const int*)d_in[12];
    float* out = (float*)d_out;

    char* ws = (char*)d_ws;
    size_t o = 0;
    auto alloc = [&](size_t bytes) -> void* {
        void* p = ws + o;
        o += (bytes + 255) & ~(size_t)255;
        return p;
    };
    // regionA: recs (14.4 MB) reused for h1/h2 (fp8, 3.2 MB each) after p2
    char* regionA = (char*)alloc((size_t)NBUK * CAP * sizeof(unsigned));
    unsigned* recs = (unsigned*)regionA;
    unsigned char* h1 = (unsigned char*)regionA;
    unsigned char* h2 = (unsigned char*)(regionA + (size_t)NN * FF);

    unsigned* packed = (unsigned*)alloc((size_t)NBUK * CAP * sizeof(unsigned));
    unsigned* xb     = (unsigned*)alloc((size_t)NN * FF);          // fp8 x
    int* cursor = (int*)alloc(NBUK * sizeof(int));
    float* sums = (float*)alloc(LL * FF * sizeof(float));          // adjacent to cursor
    int* gstart = (int*)alloc(NN * sizeof(int));
    int* gcnt   = (int*)alloc(NN * sizeof(int));
    // total ~33 MB of d_ws

    // single memset zeroes cursor + (pad) + sums
    size_t msz = (size_t)((char*)sums - (char*)cursor) + LL * FF * sizeof(float);
    hipMemsetAsync(cursor, 0, msz, stream);

    p1_scatter<<<NBLK_P1, 512, 0, stream>>>(esrc, edst, elab, x, xb, cursor, recs);
    p2_local<<<NBUK, 256, 0, stream>>>(cursor, recs, labels, packed, gstart, gcnt);

    conv_kernel<<<NN / 8, 256, 0, stream>>>((const unsigned char*)xb, h1, gstart, gcnt, packed, W1, b1, labels);
    conv_kernel<<<NN / 8, 256, 0, stream>>>(h1, h2, gstart, gcnt, packed, W2, b2, labels);
    conv_kernel<<<NN / 8, 256, 0, stream>>>(h2, h1, gstart, gcnt, packed, W3, b3, labels);

    lsum_kernel<<<128, 256, 0, stream>>>((const unsigned*)h1, labels, sums);
    resize_kernel<<<1, 256, 0, stream>>>(sums, Wr, br, out);
}